// Round 7
// baseline (546.277 us; speedup 1.0000x reference)
//
#include <hip/hip_runtime.h>
#include <math.h>

#define BATCH 4
#define NTOK  16384
#define CDIM  512
#define NH    8
#define HD    64
#define M_ROWS (BATCH*NTOK)
#define KDIM  512

typedef _Float16 f16;
typedef _Float16 f16x8 __attribute__((ext_vector_type(8)));
typedef _Float16 f16x4 __attribute__((ext_vector_type(4)));
typedef _Float16 f16x2 __attribute__((ext_vector_type(2)));
typedef float    f32x4 __attribute__((ext_vector_type(4)));

__device__ __forceinline__ void load_lds16(const void* g, void* l) {
    __builtin_amdgcn_global_load_lds(
        (const __attribute__((address_space(1))) void*)g,
        (__attribute__((address_space(3))) void*)l, 16, 0, 0);
}

// ---------------- fused prep: convert_x + both weight transposes + rope -----
__global__ __launch_bounds__(256)
void prep(const float* __restrict__ x, f16* __restrict__ xh,
          const float* __restrict__ wq, f16* __restrict__ wqt,
          const float* __restrict__ wp, f16* __restrict__ wpt,
          float* __restrict__ tab)
{
    const int bid = blockIdx.x;
    const int tid = threadIdx.x;
    __shared__ float lds[32][33];

    if (bid < 16384) {
        int i = bid * 256 + tid;
        float4 a = *(const float4*)&x[(size_t)i * 8];
        float4 b = *(const float4*)&x[(size_t)i * 8 + 4];
        f16x8 o;
        o[0]=(f16)a.x; o[1]=(f16)a.y; o[2]=(f16)a.z; o[3]=(f16)a.w;
        o[4]=(f16)b.x; o[5]=(f16)b.y; o[6]=(f16)b.z; o[7]=(f16)b.w;
        *(f16x8*)&xh[(size_t)i * 8] = o;
    } else if (bid < 16384 + 1024) {
        int tb = bid - 16384;
        const float* src; f16* dst; int N;
        if (tb < 768) { src = wq; dst = wqt; N = 1536; }
        else          { tb -= 768; src = wp; dst = wpt; N = 512; }
        int kt  = tb & 15;        // k-tile (K=512 -> 16 tiles)
        int ntl = tb >> 4;        // n-tile
        int tx = tid & 31, ty = tid >> 5;
        #pragma unroll
        for (int i = 0; i < 4; i++)
            lds[ty + 8 * i][tx] = src[(size_t)(kt * 32 + ty + 8 * i) * N + ntl * 32 + tx];
        __syncthreads();
        #pragma unroll
        for (int i = 0; i < 4; i++) {
            int p  = ty + 8 * i;
            int tc = (p < 16) ? (2 * p) : (2 * (p - 16) + 1);
            dst[(size_t)(ntl * 32 + p) * 512 + kt * 32 + tx] = (f16)lds[tx][tc];
        }
    } else {
        int idx = (bid - (16384 + 1024)) * 256 + tid;   // 0..4095 pairs
        int t   = (idx >> 4) & 127;
        int fi  = idx & 15;
        float freq = powf(10.f, -(float)fi / 16.f);
        float s, c;
        sincosf((float)t * freq, &s, &c);
        tab[idx * 2]     = c;
        tab[idx * 2 + 1] = s;
    }
}

// ---------------- fp16 MFMA GEMM, 128x128 tile, BK=64, counted-vmcnt --------
// T3+T4 upgrade of the R3 structure: double-buffered LDS (64 KB, 2 blocks/CU)
// with COUNTED vmcnt so prefetch loads stay in flight ACROSS barriers (never
// drain to 0 in-loop; m218: counted-vs-drain = +38..73%). Per K-step:
//   ds_read 16xb128 -> regs ; lgkmcnt(0) ; s_barrier     (all reads done)
//   stage(t+2) into the just-freed buffer (8 global_load_lds)
//   setprio(1) ; 32 MFMA ; setprio(0)
//   vmcnt(8)  (tile t+1 complete; tile t+2's 8 still flying) ; s_barrier
// Race-free: writes to a buffer only after the barrier proving all waves
// finished reading it; reads of tile t+1 only after vmcnt+barrier proving
// every wave's stage(t+1) completed. No other vmem ops in-loop (epilogue
// loads sit after the loop, ordered by the asm memory clobbers).
// T2 XOR-swizzle (chunk ^= row&7) on pre-swizzled global source + ds_read
// side (conflicts measured 0). XCD-swizzled grid. PERMUTED weight columns.
template<int MODE>
__global__ __launch_bounds__(256, 2)
void gemm_f16(const f16* __restrict__ A, const f16* __restrict__ Bt,
              const float* __restrict__ bias,
              float* __restrict__ Co,
              f16* __restrict__ qd, f16* __restrict__ kd, f16* __restrict__ vd,
              const float* __restrict__ tab, int ncol_tiles)
{
    __shared__ f16 As[2][128 * 64];
    __shared__ f16 Bs[2][128 * 64];
    const int tid  = threadIdx.x;
    const int lane = tid & 63;
    const int wave = tid >> 6;
    const int wy = wave >> 1, wx = wave & 1;

    const int bid = blockIdx.x;
    const int xcd = bid & 7;
    const int idx = bid >> 3;
    const int ct  = idx % ncol_tiles;
    const int rt  = (idx / ncol_tiles) * 8 + xcd;
    const int row0 = rt * 128;
    const int col0 = ct * 128;

    const int l15 = lane & 15;
    const int l4  = lane >> 4;

    f32x4 acc[4][4];
    #pragma unroll
    for (int mt = 0; mt < 4; mt++)
        #pragma unroll
        for (int nt = 0; nt < 4; nt++)
            acc[mt][nt] = (f32x4){0.f, 0.f, 0.f, 0.f};

    const int pbase = wave * 256;   // 16B-chunk base for this wave (4 issues x 64)

    auto stage = [&](int buf, int k0) {
        #pragma unroll
        for (int i = 0; i < 4; i++) {
            int p  = pbase + i * 64 + lane;   // chunk id 0..1023
            int m  = p >> 3;                  // tile row 0..127
            int jp = p & 7;                   // physical 16B chunk within row
            int j  = jp ^ (m & 7);            // logical k-chunk to fetch (swizzle)
            load_lds16(&A [(size_t)(row0 + m) * KDIM + k0 + j * 8],
                       &As[buf][(pbase + i * 64) * 8]);
            load_lds16(&Bt[(size_t)(col0 + m) * KDIM + k0 + j * 8],
                       &Bs[buf][(pbase + i * 64) * 8]);
        }
    };

    constexpr int NT = KDIM / 64;   // 8 K-tiles

    // prologue: 2 tiles in flight, wait only for tile 0 (8 of tile 1 flying)
    stage(0, 0);
    stage(1, 64);
    asm volatile("s_waitcnt vmcnt(8)" ::: "memory");
    __builtin_amdgcn_s_barrier();

    #pragma unroll
    for (int t = 0; t < NT; ++t) {
        const int cur = t & 1;
        f16x8 af[2][4], bf[2][4];
        #pragma unroll
        for (int s = 0; s < 2; s++)
            #pragma unroll
            for (int u = 0; u < 4; u++) {
                int ra = wy * 64 + u * 16 + l15;
                int rb = wx * 64 + u * 16 + l15;
                int ca = ((s << 2) | l4) ^ (ra & 7);
                int cb = ((s << 2) | l4) ^ (rb & 7);
                af[s][u] = *(const f16x8*)&As[cur][ra * 64 + ca * 8];
                bf[s][u] = *(const f16x8*)&Bs[cur][rb * 64 + cb * 8];
            }
        asm volatile("s_waitcnt lgkmcnt(0)" ::: "memory");
        if (t + 2 < NT) {
            __builtin_amdgcn_s_barrier();      // all waves done READING buf[cur]
            stage(cur, (t + 2) * 64);          // overwrite freed buffer
        }
        __builtin_amdgcn_s_setprio(1);
        #pragma unroll
        for (int s = 0; s < 2; s++)
            #pragma unroll
            for (int mt = 0; mt < 4; mt++)
                #pragma unroll
                for (int nt = 0; nt < 4; nt++)
                    acc[mt][nt] = __builtin_amdgcn_mfma_f32_16x16x32_f16(af[s][mt], bf[s][nt], acc[mt][nt], 0, 0, 0);
        __builtin_amdgcn_s_setprio(0);
        if (t + 1 < NT) {                      // protect next tile's reads
            if (t + 2 < NT)
                asm volatile("s_waitcnt vmcnt(8)" ::: "memory");  // tile t+1 done
            else
                asm volatile("s_waitcnt vmcnt(0)" ::: "memory");  // drain tail
            __builtin_amdgcn_s_barrier();
        }
    }

    if (MODE == 0) {
        // Permuted-column direct-store epilogue: lane l15 owns true cols
        // (2*l15, 2*l15+1); float2 stores. No LDS, no barriers.
        #pragma unroll
        for (int q = 0; q < 2; q++) {
            int B32 = (col0 + wx * 64 + q * 32) >> 5;
            int t0c = B32 * 32 + 2 * l15;
            float bv0 = bias[t0c];
            float bv1 = bias[t0c + 1];
            #pragma unroll
            for (int mt = 0; mt < 4; mt++)
                #pragma unroll
                for (int r = 0; r < 4; r++) {
                    int row = row0 + wy * 64 + mt * 16 + l4 * 4 + r;
                    float2 o2;
                    o2.x = acc[mt][2 * q][r]     + bv0;
                    o2.y = acc[mt][2 * q + 1][r] + bv1;
                    *(float2*)&Co[(size_t)row * CDIM + t0c] = o2;
                }
        }
    } else {
        // Permuted-column epilogue with fused RoPE+ELU for Q/K, plain for V.
        const int which = col0 >> 9;
        f16* dst = (which == 0) ? qd : (which == 1) ? kd : vd;
        const float2* tab2 = (const float2*)tab;
        #pragma unroll
        for (int q = 0; q < 2; q++) {
            int B32  = (col0 + wx * 64 + q * 32) >> 5;   // 32-col block id
            int t0   = B32 * 32 + 2 * l15;               // true col (even)
            int c512 = t0 & 511;
            float bv0 = bias[t0];
            float bv1 = bias[t0 + 1];
            int isy  = B32 & 1;                          // x-half / y-half of head
            const float2* ct = tab2 + isy * 2048 + l15;  // [isy][t][fi=l15]
            if (which == 2) {
                #pragma unroll
                for (int mt = 0; mt < 4; mt++)
                    #pragma unroll
                    for (int r = 0; r < 4; r++) {
                        int row = row0 + wy * 64 + mt * 16 + l4 * 4 + r;
                        f16x2 pk;
                        pk[0] = (f16)(acc[mt][2 * q][r]     + bv0);
                        pk[1] = (f16)(acc[mt][2 * q + 1][r] + bv1);
                        *(f16x2*)&dst[(size_t)row * CDIM + c512] = pk;
                    }
            } else {
                #pragma unroll
                for (int mt = 0; mt < 4; mt++)
                    #pragma unroll
                    for (int r = 0; r < 4; r++) {
                        int row = row0 + wy * 64 + mt * 16 + l4 * 4 + r;
                        int tok = row & (NTOK - 1);
                        int t   = isy ? (tok >> 7) : (tok & 127);
                        float2 cs = ct[t * 16];
                        float xr = acc[mt][2 * q][r]     + bv0;
                        float xi = acc[mt][2 * q + 1][r] + bv1;
                        float o_r = xr * cs.x - xi * cs.y;
                        float o_i = xr * cs.y + xi * cs.x;
                        o_r = (o_r > 0.f) ? o_r + 1.f : __expf(o_r);
                        o_i = (o_i > 0.f) ? o_i + 1.f : __expf(o_i);
                        f16x2 pk; pk[0] = (f16)o_r; pk[1] = (f16)o_i;
                        *(f16x2*)&dst[(size_t)row * CDIM + c512] = pk;
                    }
            }
        }
    }
}

// kv_kernel: 8x8 register tiles; 64B LDS per 64 FMA. Wave partials merged
// once per block through LDS, then 4096 atomics. ksum accumulated per-thread
// during staging (fixed o-slice since 256 % 8 == 0), reduced at block end.
__global__ __launch_bounds__(256, 4)
void kv_kernel(const f16* __restrict__ kk, const f16* __restrict__ vv,
               float* __restrict__ kvt, float* __restrict__ ksum)
{
    int bh = blockIdx.x;
    int b = bh >> 3, h = bh & 7;
    int t0 = blockIdx.y * 1024;
    __shared__ float ks[64][68];
    __shared__ float vs[64][68];
    int tid = threadIdx.x;
    const int wave = tid >> 6;
    const int lane = tid & 63;
    const int ly = lane >> 3;
    const int lx = lane & 7;
    const int o  = (tid & 7) * 8;     // fixed dim slice this thread stages

    float acc[8][8];
    float ksacc[8];
    #pragma unroll
    for (int r = 0; r < 8; r++) { ksacc[r] = 0.f;
        #pragma unroll
        for (int j = 0; j < 8; j++) acc[r][j] = 0.f; }

    const size_t rowbase = (size_t)b * NTOK;
    for (int tt = t0; tt < t0 + 1024; tt += 64) {
        #pragma unroll
        for (int i = 0; i < 2; i++) {
            int idx = tid + i * 256;
            int tok = idx >> 3;
            size_t g = (rowbase + tt + tok) * CDIM + h * HD + o;
            f16x8 k8 = *(const f16x8*)&kk[g];
            f16x8 v8 = *(const f16x8*)&vv[g];
            float4 klo = {(float)k8[0], (float)k8[1], (float)k8[2], (float)k8[3]};
            float4 khi = {(float)k8[4], (float)k8[5], (float)k8[6], (float)k8[7]};
            float4 vlo = {(float)v8[0], (float)v8[1], (float)v8[2], (float)v8[3]};
            float4 vhi = {(float)v8[4], (float)v8[5], (float)v8[6], (float)v8[7]};
            *(float4*)&ks[tok][o]     = klo;
            *(float4*)&ks[tok][o + 4] = khi;
            *(float4*)&vs[tok][o]     = vlo;
            *(float4*)&vs[tok][o + 4] = vhi;
            ksacc[0] += klo.x; ksacc[1] += klo.y; ksacc[2] += klo.z; ksacc[3] += klo.w;
            ksacc[4] += khi.x; ksacc[5] += khi.y; ksacc[6] += khi.z; ksacc[7] += khi.w;
        }
        __syncthreads();
        #pragma unroll
        for (int t5 = 0; t5 < 16; t5++) {
            int t = wave * 16 + t5;
            float4 ka0 = *(const float4*)&ks[t][ly * 8];
            float4 ka1 = *(const float4*)&ks[t][ly * 8 + 4];
            float4 va0 = *(const float4*)&vs[t][lx * 8];
            float4 va1 = *(const float4*)&vs[t][lx * 8 + 4];
            float ka[8] = {ka0.x, ka0.y, ka0.z, ka0.w, ka1.x, ka1.y, ka1.z, ka1.w};
            float va[8] = {va0.x, va0.y, va0.z, va0.w, va1.x, va1.y, va1.z, va1.w};
            #pragma unroll
            for (int r = 0; r < 8; r++)
                #pragma unroll
                for (int j = 0; j < 8; j++) acc[r][j] += ka[r] * va[j];
        }
        __syncthreads();
    }

    // ksum partials -> LDS (vs region is free now)
    float* ksl = &vs[0][0];
    {
        float4 a = {ksacc[0], ksacc[1], ksacc[2], ksacc[3]};
        float4 c = {ksacc[4], ksacc[5], ksacc[6], ksacc[7]};
        *(float4*)&ksl[tid * 8]     = a;
        *(float4*)&ksl[tid * 8 + 4] = c;
    }
    // merge 4 wave partials into red[e][d] (transposed), ks region reused
    float* red = &ks[0][0];
    #pragma unroll
    for (int w = 0; w < 4; w++) {
        if (wave == w) {
            #pragma unroll
            for (int j = 0; j < 8; j++) {
                int base = (lx * 8 + j) * 64 + ly * 8;
                float4 lo = {acc[0][j], acc[1][j], acc[2][j], acc[3][j]};
                float4 hi = {acc[4][j], acc[5][j], acc[6][j], acc[7][j]};
                if (w == 0) {
                    *(float4*)&red[base]     = lo;
                    *(float4*)&red[base + 4] = hi;
                } else {
                    float4 p0 = *(const float4*)&red[base];
                    float4 p1 = *(const float4*)&red[base + 4];
                    p0.x += lo.x; p0.y += lo.y; p0.z += lo.z; p0.w += lo.w;
                    p1.x += hi.x; p1.y += hi.y; p1.z += hi.z; p1.w += hi.w;
                    *(float4*)&red[base]     = p0;
                    *(float4*)&red[base + 4] = p1;
                }
            }
        }
        __syncthreads();
    }
    #pragma unroll
    for (int i = 0; i < 16; i++) {
        int idx = tid + i * 256;          // [e][d] order, contiguous
        atomicAdd(&kvt[bh * 4096 + idx], red[idx]);
    }
    if (tid < 64) {
        float s = 0.f;
        #pragma unroll
        for (int m = 0; m < 32; m++)
            s += ksl[((tid >> 3) + m * 8) * 8 + (tid & 7)];
        atomicAdd(&ksum[bh * 64 + tid], s);
    }
}

// one-shot split-precision pack of kvt fp32 -> f16 hi/lo (attn B-operands)
__global__ void kv_pack(const float* __restrict__ kvt,
                        f16* __restrict__ kvhi, f16* __restrict__ kvlo)
{
    int idx = blockIdx.x * 256 + threadIdx.x;   // grid 128 -> 32768 x4 elems
    float4 v = *(const float4*)&kvt[idx * 4];
    f16x4 hi, lo;
    hi[0] = (f16)v.x; lo[0] = (f16)(v.x - (float)hi[0]);
    hi[1] = (f16)v.y; lo[1] = (f16)(v.y - (float)hi[1]);
    hi[2] = (f16)v.z; lo[2] = (f16)(v.z - (float)hi[2]);
    hi[3] = (f16)v.w; lo[3] = (f16)(v.w - (float)hi[3]);
    *(f16x4*)&kvhi[idx * 4] = hi;
    *(f16x4*)&kvlo[idx * 4] = lo;
}

// attn via MFMA: out[n][e] = (q[n][:] @ kv[:][e]) / (q[n][:].ksum + eps).
// B-fragments (split-precision hi/lo KV) read DIRECTLY from global (16B
// contiguous, L2-resident, reused by 64 blocks per bh). A-frags straight
// from global Q. No LDS, no barriers. z in-register via 2x shfl_xor.
__global__ __launch_bounds__(256, 4)
void attn_kernel(const f16* __restrict__ q, const f16* __restrict__ kvhi,
                 const f16* __restrict__ kvlo, const float* __restrict__ ksum,
                 f16* __restrict__ attnh)
{
    int bh = blockIdx.x;
    int b = bh >> 3, h = bh & 7;
    int rc = blockIdx.y;
    int tid = threadIdx.x;
    const int lane = tid & 63;
    const int wave = tid >> 6;
    const int l15 = lane & 15;
    const int l4  = lane >> 4;

    // B fragments from global, reused for all 4 row tiles
    f16x8 bhi[2][4], blo[2][4];
    #pragma unroll
    for (int s = 0; s < 2; s++)
        #pragma unroll
        for (int nt = 0; nt < 4; nt++) {
            int e = nt * 16 + l15;
            size_t gb = (size_t)bh * 4096 + e * 64 + s * 32 + l4 * 8;
            bhi[s][nt] = *(const f16x8*)&kvhi[gb];
            blo[s][nt] = *(const f16x8*)&kvlo[gb];
        }
    // per-lane ksum slice: d = s*32 + l4*8 + j
    float ksA[2][8];
    #pragma unroll
    for (int s = 0; s < 2; s++)
        #pragma unroll
        for (int j = 0; j < 8; j++)
            ksA[s][j] = ksum[bh * 64 + s * 32 + l4 * 8 + j];

    const size_t qbase = ((size_t)b * NTOK + rc * 256 + wave * 64) * CDIM + (size_t)h * HD;

    #pragma unroll
    for (int mt = 0; mt < 4; mt++) {
        f16x8 af[2];
        #pragma unroll
        for (int s = 0; s < 2; s++)
            af[s] = *(const f16x8*)&q[qbase + (size_t)(mt * 16 + l15) * CDIM + s * 32 + l4 * 8];

        // z for row mt*16 + l15
        float zp = 0.f;
        #pragma unroll
        for (int s = 0; s < 2; s++)
            #pragma unroll
            for (int j = 0; j < 8; j++)
                zp += (float)af[s][j] * ksA[s][j];
        zp += __shfl_xor(zp, 16, 64);
        zp += __shfl_xor(zp, 32, 64);
        float zinv = 1.f / (zp + 1e-6f);

        f32x4 acc[4];
        #pragma unroll
        for (int nt = 0; nt < 4; nt++) acc[nt] = (f32x4){0.f, 0.f, 0.f, 0.f};
        #pragma unroll
        for (int s = 0; s < 2; s++)
            #pragma unroll
            for (int nt = 0; nt < 4; nt++) {
                acc[nt] = __builtin_amdgcn_mfma_f32_16x16x32_f16(af[s], bhi[s][nt], acc[nt], 0, 0, 0);
                acc[nt] = __builtin_amdgcn_mfma_f32_16x16x32_f16(af[s], blo[s][nt], acc[nt], 0, 0, 0);
            }

        #pragma unroll
        for (int r = 0; r < 4; r++) {
            float zr = __shfl(zinv, l4 * 4 + r, 64);   // z from lane l15==row
            size_t orow = qbase + (size_t)(mt * 16 + l4 * 4 + r) * CDIM;
            #pragma unroll
            for (int nt = 0; nt < 4; nt++)
                attnh[orow + nt * 16 + l15] = (f16)(acc[nt][r] * zr);
        }
    }
}

extern "C" void kernel_launch(void* const* d_in, const int* in_sizes, int n_in,
                              void* d_out, int out_size, void* d_ws, size_t ws_size,
                              hipStream_t stream)
{
    const float* x      = (const float*)d_in[0];
    const float* w_qkv  = (const float*)d_in[1];
    const float* b_qkv  = (const float*)d_in[2];
    const float* w_proj = (const float*)d_in[3];
    const float* b_proj = (const float*)d_in[4];
    float* out = (float*)d_out;
    char*  ws  = (char*)d_ws;

    const size_t NCB = (size_t)M_ROWS * CDIM * sizeof(f16);   // 64 MiB
    f16*   xh   = (f16*)(ws);
    f16*   qh   = (f16*)(ws + NCB * 1);
    f16*   kh   = (f16*)(ws + NCB * 2);
    f16*   vh   = (f16*)(ws + NCB * 3);          // reused as attn_h after kv_kernel
    f16*   wqt  = (f16*)(ws + NCB * 4);
    f16*   wpt  = (f16*)(ws + NCB * 4 + (1536 * 512) * sizeof(f16));
    float* tab  = (float*)(ws + NCB * 4 + (1536 * 512 + 512 * 512) * sizeof(f16));
    float* kvp  = tab + 8192;
    float* ksum = kvp + 32 * 4096;
    f16*   kvhi = (f16*)(ksum + 32 * 64);
    f16*   kvlo = kvhi + 32 * 4096;

    hipMemsetAsync(kvp, 0, (32 * 4096 + 32 * 64) * sizeof(float), stream);
    prep<<<16384 + 1024 + 16, 256, 0, stream>>>(x, xh, w_qkv, wqt, w_proj, wpt, tab);

    gemm_f16<1><<<6144, 256, 0, stream>>>(xh, wqt, b_qkv,
                                          nullptr, qh, kh, vh, tab, 12);
    kv_kernel<<<dim3(32, 16), 256, 0, stream>>>(kh, vh, kvp, ksum);
    kv_pack<<<128, 256, 0, stream>>>(kvp, kvhi, kvlo);
    attn_kernel<<<dim3(32, 64), 256, 0, stream>>>(qh, kvhi, kvlo, ksum, vh);
    gemm_f16<0><<<2048, 256, 0, stream>>>(vh, wpt, b_proj,
                                          out, nullptr, nullptr, nullptr, nullptr, 4);
}